// Round 6
// baseline (154.315 us; speedup 1.0000x reference)
//
#include <hip/hip_runtime.h>
#include <hip/hip_bf16.h>

typedef unsigned int u32;
typedef unsigned short u16;
typedef __attribute__((ext_vector_type(8))) short short8;
typedef __attribute__((ext_vector_type(4))) float f32x4;

#define DEVI __device__ __forceinline__

DEVI float asf(u32 u){ union{u32 i; float f;} v; v.i=u; return v.f; }
DEVI u16 f2b(float x){ u32 b = __float_as_uint(x); u32 r = b + 0x7fffu + ((b>>16)&1u); return (u16)(r>>16); }
DEVI float b2f(u16 h){ return asf(((u32)h)<<16); }
DEVI float lk(float x){ return x > 0.f ? x : 0.01f*x; }
DEVI short8 lds8(const u16* p){ return *reinterpret_cast<const short8*>(p); }

#define MFMA(a,b,c) __builtin_amdgcn_mfma_f32_16x16x32_bf16((a),(b),(c),0,0,0)

// ---- weight fragment regions in d_ws (u16 elements) ----
// TOTAL = 206848 bytes — MUST stay < 207872 (round-3-proven ws_size floor;
// round 4 at 218112 B overran d_ws and corrupted the harness pristine copy).
// layout consumed as: frag[ (tile*64 + lane)*8 + j ]  with col=lane&15, k=(lane>>4)*8+j
#define FRAG_P4_OFF 36864   // P3: 24nt x 3ks  (s_w|sa_w|sq_w, K 96 zero-padded)
#define FRAG_P8_OFF 86016   // P4: 24nt x 4ks  (q_w|k_w|v_w, K 128)
#define FRAG_P9_OFF 102400  // P8: 4nt x 8ks   (f1_w, K 256)
#define FRAG_TOTAL  103424  // P9: 1nt x 2ks   (f2_w, K 64)
// conv weight fragments (FC1/FC2) are built per-block in LDS — NOT in d_ws.

__global__ void prelude_k(const float* __restrict__ sw, const float* __restrict__ saw,
                          const float* __restrict__ sqw,
                          const float* __restrict__ qw, const float* __restrict__ kw,
                          const float* __restrict__ vw,
                          const float* __restrict__ f1w, const float* __restrict__ f2w,
                          u16* __restrict__ frag)
{
    int idx = blockIdx.x*256 + threadIdx.x;
    if (idx >= FRAG_TOTAL) return;
    if (idx < FRAG_P4_OFF) {
        int j = idx & 7, lane = (idx>>3)&63, r2 = idx>>9;
        int ks = r2 % 3, nt = r2 / 3;
        int fl = lane&15, kg = lane>>4;
        int k = ks*32 + kg*8 + j;
        float w = 0.f;
        if (nt < 8)       { int c = nt*16+fl;      if (k < 66) w = sw[c*66+k]; }
        else if (nt < 16) { int c = (nt-8)*16+fl;  if (k < 82) w = saw[c*82+k]; }
        else              { int c = (nt-16)*16+fl; if (k < 66) w = sqw[c*66+k]; }
        frag[idx] = f2b(w);
    } else if (idx < FRAG_P8_OFF) {
        int e = idx - FRAG_P4_OFF;
        int j = e&7, lane = (e>>3)&63, r2 = e>>9;
        int ks = r2 & 3, nt = r2 >> 2;
        int fl = lane&15, kg = lane>>4;
        int k = ks*32 + kg*8 + j;
        float w;
        if (nt < 8)       w = qw[(nt*16+fl)*128 + k];
        else if (nt < 16) w = kw[((nt-8)*16+fl)*128 + k];
        else              w = vw[((nt-16)*16+fl)*128 + k];
        frag[idx] = f2b(w);
    } else if (idx < FRAG_P9_OFF) {
        int e = idx - FRAG_P8_OFF;
        int j = e&7, lane = (e>>3)&63, r2 = e>>9;
        int ks = r2&7, nt = r2>>3;
        int k = ks*32 + (lane>>4)*8 + j;
        frag[idx] = f2b(f1w[(nt*16+(lane&15))*256 + k]);
    } else {
        int e = idx - FRAG_P9_OFF;
        int j = e&7, lane = (e>>3)&63, r2 = e>>9;   // r2 = ks in {0,1}
        int k = r2*32 + (lane>>4)*8 + j;
        frag[idx] = f2b(f2w[(lane&15)*64 + k]);
    }
}

// ---- LDS map (bytes) — packed to 53,760 B => 3 blocks/CU (was 60,416 => 2) ----
// row strides odd multiples of 16B for aligned ds_read_b128 without 16-way conflicts
//
// region    off    size   lifetime
// STh       0      8704   u16[32][136] states (conv32|pos2|oh32|act16|pad) P0w->P3r
// Qh        0      8704   u16[32][136] queries (pre-scaled)                P4w->P5r  (STh dead)
// SQh       8704   8704   u16[32][136]                                     P3w->P8r
// IM        8704   23040  u16[288][40] im2col + FC1 frags cols32..39       P0w->P1r  (pre-P3)
// SEh       17408  8704   u16[32][136]                                     P3w->P4r  (IM dead)
// SCf       17408  4608   f32[32][36]  scores                              P5w->P6r  (SEh dead)
// H1h       17408  4608   u16[32][72]  f1 out                              P8w->P9r  (SCf dead)
// SAh       26112  8704   u16[32][136]                                     P3w->P4r  (IM dead)
// W32h      26112  2560   u16[32][40]  softmax weights, zero diag          P6w->P7r  (SAh dead)
// C1h       31744  10752  u16[32][168] conv1 out                           P0w(pad)/P1w->P2r
// Kh        34816  8704   u16[32][136] keys                                P4w->P5r  (C1h dead)
// AGGh      34816  8704   u16[32][136] agg                                 P7w->P8r  (Kh dead)
// FC2L      42496  10240  u16[5120]    conv2 w frags                       P0w->P2r
// Vt        43520  10240  u16[128][40] values TRANSPOSED                   P4w->P7r  (FC2L dead)
#define L_STH 0
#define L_QH  0
#define L_SQH 8704
#define L_IM  8704
#define L_SEH 17408
#define L_SCF 17408
#define L_H1  17408
#define L_SAH 26112
#define L_W32 26112
#define L_C1H 31744
#define L_KH  34816
#define L_AGG 34816
#define L_FC2 42496
#define L_VT  43520
#define SMEM_BYTES 53760

__global__ __launch_bounds__(512, 6)
void fused_kernel(const float* __restrict__ xs, const float* __restrict__ pos,
                  const float* __restrict__ oh, const float* __restrict__ act,
                  const float* __restrict__ c1w, const float* __restrict__ c1b,
                  const float* __restrict__ c2w, const float* __restrict__ c2b,
                  const float* __restrict__ sb,  const float* __restrict__ sab,
                  const float* __restrict__ sqb,
                  const float* __restrict__ qb,  const float* __restrict__ kb,
                  const float* __restrict__ vb,
                  const float* __restrict__ f1b, const float* __restrict__ f2b_,
                  float* __restrict__ outv, float* __restrict__ outw,
                  const u16* __restrict__ frag)
{
    __shared__ __align__(16) char smem[SMEM_BYTES];

    const int b = blockIdx.x, tid = threadIdx.x;
    const int lane = tid & 63, wv = tid >> 6;
    const int fl = lane & 15, kg = lane >> 4;

    u16* STh = (u16*)(smem + L_STH);
    u16* SQh = (u16*)(smem + L_SQH);
    u16* SEh = (u16*)(smem + L_SEH);
    u16* SAh = (u16*)(smem + L_SAH);
    u16* Qh  = (u16*)(smem + L_QH);
    u16* Kh  = (u16*)(smem + L_KH);
    u16* Vt  = (u16*)(smem + L_VT);
    u16* IM   = (u16*)(smem + L_IM);
    u16* C1h  = (u16*)(smem + L_C1H);
    u16* FC2L = (u16*)(smem + L_FC2);
    float* SCf = (float*)(smem + L_SCF);
    u16* W32h = (u16*)(smem + L_W32);
    u16* AGGh = (u16*)(smem + L_AGG);
    u16* H1h  = (u16*)(smem + L_H1);
    const u16* F3  = frag;
    const u16* F4  = frag + FRAG_P4_OFF;
    const u16* F8  = frag + FRAG_P8_OFF;
    const u16* F9  = frag + FRAG_P9_OFF;

    // ---------------- P0 (merged): STh stage, conv-w frags, im2col direct from global ----------------
    for (int i = tid; i < 64; i += 512)   { int n=i>>1, j=i&1;  STh[n*136+32+j] = f2b(pos[(b*32+n)*2+j]); }
    for (int i = tid; i < 1024; i += 512) { int n=i>>5, m=i&31; STh[n*136+34+m] = f2b(oh[(b*32+n)*32+m]); }
    { int n=tid>>4, j=tid&15; STh[n*136+66+j] = f2b(act[(b*32+n)*16+j]); }
    for (int i = tid; i < 448; i += 512)  { int n=i/14, j=i-n*14; STh[n*136+82+j] = 0; }  // zero K-pad 82..95
    {   // FC1: conv1 w fragments at IM cols 32..39 (16B-aligned per lane)
        int j = tid & 7, l2 = tid >> 3;   // l2 in 0..63
        int k = (l2 >> 4)*8 + j;
        IM[l2*40 + 32 + j] = f2b((k < 27) ? c1w[(l2 & 15)*27 + k] : 0.f);
    }
    for (int e = tid; e < 5120; e += 512) {  // FC2: conv2 w fragments
        int j = e & 7, l2 = (e >> 3) & 63, r2 = e >> 9;   // r2 = nt*5+ks
        int ks = r2 % 5, nt = r2 / 5;
        int k = ks*32 + (l2 >> 4)*8 + j;
        FC2L[e] = f2b((k < 144) ? c2w[(nt*16 + (l2 & 15))*144 + k] : 0.f);
    }
    {   // im2col: IM[row][k] <- xs gather (block working set 9.6 KB, L1-resident)
        const float* xp = xs + b*2400;
        for (int e = tid; e < 9216; e += 512) {
            int row = e >> 5, k = e & 31;
            int n = row / 9, p = row - n*9;
            float v = 0.f;
            if (k < 27) {
                int ic = k / 9, q = k - ic*9;
                int y = p/3 + q/3, x = (p - (p/3)*3) + (q - (q/3)*3);
                v = xp[n*75 + ic*25 + y*5 + x];
            }
            IM[row*40 + k] = f2b(v);
        }
    }
    for (int i = tid; i < 768; i += 512) { int n = i/24, j = i - n*24; C1h[n*168 + 144 + j] = 0; }
    __syncthreads();

    // ---------------- P1: conv1 via MFMA  [288x32]@[32x16] -> C1h[n][oc*9+p] ----------------
    for (int t = wv; t < 18; t += 8) {
        f32x4 acc = {0.f,0.f,0.f,0.f};
        acc = MFMA(lds8(IM + (t*16 + fl)*40 + kg*8), lds8(IM + lane*40 + 32), acc);
        float bv = c1b[fl];
        #pragma unroll
        for (int r = 0; r < 4; ++r) {
            int row = t*16 + kg*4 + r;
            int n = row / 9, p = row - n*9;
            C1h[n*168 + fl*9 + p] = f2b(lk(acc[r] + bv));
        }
    }
    __syncthreads();

    // ---------------- P2: conv2 via MFMA  [32x160]@[160x32] -> STh cols 0..31 ----------------
    if (wv < 4) {
        int mt = wv >> 1, nt = wv & 1;
        f32x4 acc = {0.f,0.f,0.f,0.f};
        const u16* ap = C1h + (mt*16 + fl)*168 + kg*8;
        const u16* bp = FC2L + ((nt*5)*64 + lane)*8;
        #pragma unroll
        for (int ks = 0; ks < 5; ++ks)
            acc = MFMA(lds8(ap + ks*32), lds8(bp + ks*512), acc);
        float bv = c2b[nt*16 + fl];
        #pragma unroll
        for (int r = 0; r < 4; ++r)
            STh[(mt*16 + kg*4 + r)*136 + nt*16 + fl] = f2b(lk(acc[r] + bv));
    }
    __syncthreads();

    // ---------------- P3: [32x96]@[96x384] -> SE|SA|SQ (MFMA, bias+leaky) ----------------
    for (int t = wv; t < 48; t += 8) {
        int nt = t >> 1, mt = t & 1;
        f32x4 acc = {0.f,0.f,0.f,0.f};
        const u16* ap = STh + (mt*16 + fl)*136 + kg*8;
        const u16* bp = F3 + ((nt*3)*64 + lane)*8;
        #pragma unroll
        for (int ks = 0; ks < 3; ++ks)
            acc = MFMA(lds8(ap + ks*32), lds8(bp + ks*512), acc);
        u16* dst; const float* bias; int colOff;
        if (nt < 8)       { dst = SEh; bias = sb;  colOff = nt*16; }
        else if (nt < 16) { dst = SAh; bias = sab; colOff = (nt-8)*16; }
        else              { dst = SQh; bias = sqb; colOff = (nt-16)*16; }
        float bv = bias[colOff + fl];
        int rowb = mt*16 + kg*4;
        #pragma unroll
        for (int r = 0; r < 4; ++r)
            dst[(rowb+r)*136 + colOff + fl] = f2b(lk(acc[r] + bv));
    }
    __syncthreads();

    // ---------------- P4: Q|K|V (MFMA; Q pre-scaled; V transposed) ----------------
    for (int t = wv; t < 48; t += 8) {
        int nt = t >> 1, mt = t & 1;
        const u16* A = (nt < 8) ? SEh : SAh;
        f32x4 acc = {0.f,0.f,0.f,0.f};
        const u16* ap = A + (mt*16 + fl)*136 + kg*8;
        const u16* bp = F4 + ((nt*4)*64 + lane)*8;
        #pragma unroll
        for (int ks = 0; ks < 4; ++ks)
            acc = MFMA(lds8(ap + ks*32), lds8(bp + ks*512), acc);
        int rowb = mt*16 + kg*4;
        if (nt < 8) {
            float bv = qb[nt*16 + fl];
            #pragma unroll
            for (int r = 0; r < 4; ++r)
                Qh[(rowb+r)*136 + nt*16 + fl] = f2b((acc[r] + bv)*0.08838834764831845f);
        } else if (nt < 16) {
            float bv = kb[(nt-8)*16 + fl];
            #pragma unroll
            for (int r = 0; r < 4; ++r)
                Kh[(rowb+r)*136 + (nt-8)*16 + fl] = f2b(acc[r] + bv);
        } else {
            int c = (nt-16)*16 + fl;
            float bv = vb[c];
            #pragma unroll
            for (int r = 0; r < 4; ++r)
                Vt[c*40 + rowb + r] = f2b(acc[r] + bv);
        }
    }
    __syncthreads();

    // ---------------- P5: score = Q @ K^T ----------------
    if (wv < 4) {
        int nt = wv >> 1, mt = wv & 1;
        f32x4 acc = {0.f,0.f,0.f,0.f};
        const u16* ap = Qh + (mt*16 + fl)*136 + kg*8;
        const u16* bp = Kh + (nt*16 + fl)*136 + kg*8;
        #pragma unroll
        for (int ks = 0; ks < 4; ++ks)
            acc = MFMA(lds8(ap + ks*32), lds8(bp + ks*32), acc);
        int rowb = mt*16 + kg*4;
        #pragma unroll
        for (int r = 0; r < 4; ++r)
            SCf[(rowb+r)*36 + nt*16 + fl] = acc[r];
    }
    __syncthreads();

    // ---------------- P6: off-diagonal softmax -> outw + W32 (zero diag) ----------------
    {
        int n = tid >> 4, g = tid & 15;
        int m0 = (g < n) ? g : g+1;
        int j1 = g + 16;
        bool v1 = j1 < 31;
        int m1 = (j1 < n) ? j1 : j1+1;
        float e0 = SCf[n*36 + m0];
        float e1 = v1 ? SCf[n*36 + m1] : -1e30f;
        float mx = fmaxf(e0, e1);
        #pragma unroll
        for (int d = 8; d; d >>= 1) mx = fmaxf(mx, __shfl_xor(mx, d, 16));
        float x0 = __expf(e0 - mx);
        float x1 = v1 ? __expf(e1 - mx) : 0.f;
        float s = x0 + x1;
        #pragma unroll
        for (int d = 8; d; d >>= 1) s += __shfl_xor(s, d, 16);
        float inv = 1.f/s;
        float w0 = x0*inv, w1 = x1*inv;
        W32h[n*40 + m0] = f2b(w0);
        if (v1) W32h[n*40 + m1] = f2b(w1);
        if (g == 0) W32h[n*40 + n] = 0;
        float* wp = outw + (b*32 + n)*31;
        wp[g] = w0;
        if (v1) wp[j1] = w1;
    }
    __syncthreads();

    // ---------------- P7: agg = W32 @ V  (B from Vt) ----------------
    for (int t = wv; t < 16; t += 8) {
        int nt = t >> 1, mt = t & 1;
        f32x4 acc = {0.f,0.f,0.f,0.f};
        acc = MFMA(lds8(W32h + (mt*16 + fl)*40 + kg*8),
                   lds8(Vt + (nt*16 + fl)*40 + kg*8), acc);
        int rowb = mt*16 + kg*4;
        #pragma unroll
        for (int r = 0; r < 4; ++r)
            AGGh[(rowb+r)*136 + nt*16 + fl] = f2b(acc[r]);
    }
    __syncthreads();

    // ---------------- P8: f1 ([32x256]@[256x64], K split sq|agg, bias+leaky) ----------------
    {
        int t = wv;
        int nt = t >> 1, mt = t & 1;
        f32x4 acc = {0.f,0.f,0.f,0.f};
        const u16* bp = F8 + ((nt*8)*64 + lane)*8;
        #pragma unroll
        for (int ks = 0; ks < 8; ++ks) {
            const u16* ap = ((ks < 4) ? SQh : AGGh) + (mt*16 + fl)*136 + (ks&3)*32 + kg*8;
            acc = MFMA(lds8(ap), lds8(bp + ks*512), acc);
        }
        float bv = f1b[nt*16 + fl];
        int rowb = mt*16 + kg*4;
        #pragma unroll
        for (int r = 0; r < 4; ++r)
            H1h[(rowb+r)*72 + nt*16 + fl] = f2b(lk(acc[r] + bv));
    }
    __syncthreads();

    // ---------------- P9: f2 ([32x64]@[64x16]) -> value out ----------------
    if (wv < 2) {
        int mt = wv;
        f32x4 acc = {0.f,0.f,0.f,0.f};
        const u16* ap = H1h + (mt*16 + fl)*72 + kg*8;
        const u16* bp = F9 + lane*8;
        #pragma unroll
        for (int ks = 0; ks < 2; ++ks)
            acc = MFMA(lds8(ap + ks*32), lds8(bp + ks*512), acc);
        float bv = f2b_[fl];
        int rowb = mt*16 + kg*4;
        #pragma unroll
        for (int r = 0; r < 4; ++r)
            outv[(b*32 + rowb + r)*16 + fl] = acc[r] + bv;
    }
}

extern "C" void kernel_launch(void* const* d_in, const int* in_sizes, int n_in,
                              void* d_out, int out_size, void* d_ws, size_t ws_size,
                              hipStream_t stream) {
    const int B = in_sizes[0] / (32*75);
    u16* frag = (u16*)d_ws;

    // indices: 0 xs,1 pos,2 oh,3 policies,4 act, 5 c1w,6 c1b,7 c2w,8 c2b,
    // 9 sa_w,10 sa_b,11 s_w,12 s_b, 13 k_w,14 k_b, 15 q_w,16 q_b, 17 v_w,18 v_b,
    // 19 sq_w,20 sq_b, 21 f1_w,22 f1_b, 23 f2_w,24 f2_b
    const int PRE_GRID = (FRAG_TOTAL + 255)/256;
    prelude_k<<<PRE_GRID, 256, 0, stream>>>(
        (const float*)d_in[11], (const float*)d_in[9],  (const float*)d_in[19],
        (const float*)d_in[15], (const float*)d_in[13], (const float*)d_in[17],
        (const float*)d_in[21], (const float*)d_in[23], frag);

    fused_kernel<<<B, 512, 0, stream>>>(
        (const float*)d_in[0],  (const float*)d_in[1],  (const float*)d_in[2],
        (const float*)d_in[4],
        (const float*)d_in[5],  (const float*)d_in[6],
        (const float*)d_in[7],  (const float*)d_in[8],
        (const float*)d_in[12], (const float*)d_in[10], (const float*)d_in[20],
        (const float*)d_in[16], (const float*)d_in[14], (const float*)d_in[18],
        (const float*)d_in[22], (const float*)d_in[24],
        (float*)d_out, (float*)d_out + (size_t)B*32*16, frag);
}

// Round 8
// 152.373 us; speedup vs baseline: 1.0127x; 1.0127x over previous
//
#include <hip/hip_runtime.h>
#include <hip/hip_bf16.h>

typedef unsigned int u32;
typedef unsigned short u16;
typedef __attribute__((ext_vector_type(8))) short short8;
typedef __attribute__((ext_vector_type(4))) float f32x4;

#define DEVI __device__ __forceinline__

DEVI float asf(u32 u){ union{u32 i; float f;} v; v.i=u; return v.f; }
DEVI u16 f2b(float x){ u32 b = __float_as_uint(x); u32 r = b + 0x7fffu + ((b>>16)&1u); return (u16)(r>>16); }
DEVI float lk(float x){ return x > 0.f ? x : 0.01f*x; }
DEVI short8 lds8(const u16* p){ return *reinterpret_cast<const short8*>(p); }

#define MFMA(a,b,c) __builtin_amdgcn_mfma_f32_16x16x32_bf16((a),(b),(c),0,0,0)

// ---- weight fragment regions in d_ws (u16 elements) ----
// TOTAL = 206848 bytes — MUST stay < 207872 (round-3-proven ws_size floor;
// round 4 at 218112 B overran d_ws and corrupted the harness pristine copy).
#define FRAG_P4_OFF 36864   // P3: 24nt x 3ks  (s_w|sa_w|sq_w, K 96 zero-padded)
#define FRAG_P8_OFF 86016   // P4: 24nt x 4ks  (q_w|k_w|v_w, K 128)
#define FRAG_P9_OFF 102400  // P8: 4nt x 8ks   (f1_w, K 256)
#define FRAG_TOTAL  103424  // P9: 1nt x 2ks   (f2_w, K 64)

__global__ void prelude_k(const float* __restrict__ sw, const float* __restrict__ saw,
                          const float* __restrict__ sqw,
                          const float* __restrict__ qw, const float* __restrict__ kw,
                          const float* __restrict__ vw,
                          const float* __restrict__ f1w, const float* __restrict__ f2w,
                          u16* __restrict__ frag)
{
    int idx = blockIdx.x*256 + threadIdx.x;
    if (idx >= FRAG_TOTAL) return;
    if (idx < FRAG_P4_OFF) {
        int j = idx & 7, lane = (idx>>3)&63, r2 = idx>>9;
        int ks = r2 % 3, nt = r2 / 3;
        int fl = lane&15, kg = lane>>4;
        int k = ks*32 + kg*8 + j;
        float w = 0.f;
        if (nt < 8)       { int c = nt*16+fl;      if (k < 66) w = sw[c*66+k]; }
        else if (nt < 16) { int c = (nt-8)*16+fl;  if (k < 82) w = saw[c*82+k]; }
        else              { int c = (nt-16)*16+fl; if (k < 66) w = sqw[c*66+k]; }
        frag[idx] = f2b(w);
    } else if (idx < FRAG_P8_OFF) {
        int e = idx - FRAG_P4_OFF;
        int j = e&7, lane = (e>>3)&63, r2 = e>>9;
        int ks = r2 & 3, nt = r2 >> 2;
        int fl = lane&15, kg = lane>>4;
        int k = ks*32 + kg*8 + j;
        float w;
        if (nt < 8)       w = qw[(nt*16+fl)*128 + k];
        else if (nt < 16) w = kw[((nt-8)*16+fl)*128 + k];
        else              w = vw[((nt-16)*16+fl)*128 + k];
        frag[idx] = f2b(w);
    } else if (idx < FRAG_P9_OFF) {
        int e = idx - FRAG_P8_OFF;
        int j = e&7, lane = (e>>3)&63, r2 = e>>9;
        int ks = r2&7, nt = r2>>3;
        int k = ks*32 + (lane>>4)*8 + j;
        frag[idx] = f2b(f1w[(nt*16+(lane&15))*256 + k]);
    } else {
        int e = idx - FRAG_P9_OFF;
        int j = e&7, lane = (e>>3)&63, r2 = e>>9;   // r2 = ks in {0,1}
        int k = r2*32 + (lane>>4)*8 + j;
        frag[idx] = f2b(f2w[(lane&15)*64 + k]);
    }
}

// ---- LDS map (bytes) — 53,760 B (same as r6; liveness unchanged) ----
#define L_STH 0       // u16[32][136] states            P0w->P3r
#define L_QH  0       // u16[32][136] queries           P4w->P5r (STh dead)
#define L_SQH 8704    // u16[32][136] sq embedding      P3w->P8r
#define L_IM  8704    // u16[288][40] im2col+FC1 frags  P0w->P1r (pre-P3)
#define L_SEH 17408   // u16[32][136]                   P3w->P4r (IM dead)
#define L_H1  17408   // u16[32][72]  f1 out            P8w->P9r (SEh dead)
#define L_SAH 26112   // u16[32][136]                   P3w->P4r (IM dead)
#define L_W32 26112   // u16[32][40]  softmax w         P56w->P7r (SAh dead)
#define L_C1H 31744   // u16[32][168] conv1 out         P0(pad)/P1w->P2r
#define L_KH  34816   // u16[32][136] keys              P4w->P5r (C1h dead)
#define L_AGG 34816   // u16[32][136] agg               P7w->P8r (Kh dead)
#define L_FC2 42496   // u16[5120]    conv2 w frags     P0w->P2r
#define L_VT  43520   // u16[128][40] values TRANSPOSED P4w->P7r (FC2L dead)
#define SMEM_BYTES 53760

__global__ __launch_bounds__(512, 4)
void fused_kernel(const float* __restrict__ xs, const float* __restrict__ pos,
                  const float* __restrict__ oh, const float* __restrict__ act,
                  const float* __restrict__ c1w, const float* __restrict__ c1b,
                  const float* __restrict__ c2w, const float* __restrict__ c2b,
                  const float* __restrict__ sb,  const float* __restrict__ sab,
                  const float* __restrict__ sqb,
                  const float* __restrict__ qb,  const float* __restrict__ kb,
                  const float* __restrict__ vb,
                  const float* __restrict__ f1b, const float* __restrict__ f2b_,
                  float* __restrict__ outv, float* __restrict__ outw,
                  const u16* __restrict__ frag)
{
    __shared__ __align__(16) char smem[SMEM_BYTES];

    const int b = blockIdx.x, tid = threadIdx.x;
    const int lane = tid & 63, wv = tid >> 6;
    const int fl = lane & 15, kg = lane >> 4;
    const int mt = wv & 1, nb = wv >> 1;

    u16* STh = (u16*)(smem + L_STH);
    u16* SQh = (u16*)(smem + L_SQH);
    u16* SEh = (u16*)(smem + L_SEH);
    u16* SAh = (u16*)(smem + L_SAH);
    u16* Qh  = (u16*)(smem + L_QH);
    u16* Kh  = (u16*)(smem + L_KH);
    u16* Vt  = (u16*)(smem + L_VT);
    u16* IM   = (u16*)(smem + L_IM);
    u16* C1h  = (u16*)(smem + L_C1H);
    u16* FC2L = (u16*)(smem + L_FC2);
    u16* W32h = (u16*)(smem + L_W32);
    u16* AGGh = (u16*)(smem + L_AGG);
    u16* H1h  = (u16*)(smem + L_H1);
    const u16* F3  = frag;
    const u16* F4  = frag + FRAG_P4_OFF;
    const u16* F8  = frag + FRAG_P8_OFF;
    const u16* F9  = frag + FRAG_P9_OFF;

    // ---------------- P0: staging (im2col direct from global, conv-w frags to LDS) ----------------
    for (int i = tid; i < 64; i += 512)   { int n=i>>1, j=i&1;  STh[n*136+32+j] = f2b(pos[(b*32+n)*2+j]); }
    for (int i = tid; i < 1024; i += 512) { int n=i>>5, m=i&31; STh[n*136+34+m] = f2b(oh[(b*32+n)*32+m]); }
    { int n=tid>>4, j=tid&15; STh[n*136+66+j] = f2b(act[(b*32+n)*16+j]); }
    for (int i = tid; i < 448; i += 512)  { int n=i/14, j=i-n*14; STh[n*136+82+j] = 0; }
    {   // FC1 frags at IM cols 32..39
        int j = tid & 7, l2 = tid >> 3;
        int k = (l2 >> 4)*8 + j;
        IM[l2*40 + 32 + j] = f2b((k < 27) ? c1w[(l2 & 15)*27 + k] : 0.f);
    }
    for (int e = tid; e < 5120; e += 512) {  // FC2 frags
        int j = e & 7, l2 = (e >> 3) & 63, r2 = e >> 9;
        int ks = r2 % 5, nt = r2 / 5;
        int k = ks*32 + (l2 >> 4)*8 + j;
        FC2L[e] = f2b((k < 144) ? c2w[(nt*16 + (l2 & 15))*144 + k] : 0.f);
    }
    {   // im2col (unrolled: 18 independent gathers batched)
        const float* xp = xs + b*2400;
        #pragma unroll
        for (int i = 0; i < 18; ++i) {
            int e = tid + i*512;
            int row = e >> 5, k = e & 31;
            int n = row / 9, p = row - n*9;
            float v = 0.f;
            if (k < 27) {
                int ic = k / 9, q = k - ic*9;
                int y = p/3 + q/3, x = (p - (p/3)*3) + (q - (q/3)*3);
                v = xp[n*75 + ic*25 + y*5 + x];
            }
            IM[row*40 + k] = f2b(v);
        }
    }
    for (int i = tid; i < 768; i += 512) { int n = i/24, j = i - n*24; C1h[n*168 + 144 + j] = 0; }
    __syncthreads();

    // ---------------- P1: conv1 via MFMA ----------------
    {
        short8 bw = lds8(IM + lane*40 + 32);   // FC1 fragment, reused across tiles
        for (int t = wv; t < 18; t += 8) {
            f32x4 acc = {0.f,0.f,0.f,0.f};
            acc = MFMA(lds8(IM + (t*16 + fl)*40 + kg*8), bw, acc);
            float bv = c1b[fl];
            #pragma unroll
            for (int r = 0; r < 4; ++r) {
                int row = t*16 + kg*4 + r;
                int n = row / 9, p = row - n*9;
                C1h[n*168 + fl*9 + p] = f2b(lk(acc[r] + bv));
            }
        }
    }
    __syncthreads();

    // ---------------- P2: conv2 via MFMA (waves 0-3) ----------------
    if (wv < 4) {
        int m2 = wv >> 1, n2 = wv & 1;
        f32x4 acc = {0.f,0.f,0.f,0.f};
        const u16* ap = C1h + (m2*16 + fl)*168 + kg*8;
        const u16* bp = FC2L + ((n2*5)*64 + lane)*8;
        #pragma unroll
        for (int ks = 0; ks < 5; ++ks)
            acc = MFMA(lds8(ap + ks*32), lds8(bp + ks*512), acc);
        float bv = c2b[n2*16 + fl];
        #pragma unroll
        for (int r = 0; r < 4; ++r)
            STh[(m2*16 + kg*4 + r)*136 + n2*16 + fl] = f2b(lk(acc[r] + bv));
    }
    // cross-barrier prefetch: P3 first B-tile (global, no LDS hazard)
    short8 pb0, pb1, pb2;
    {
        const short8* p = (const short8*)(F3 + ((nb*3)*64 + lane)*8);
        pb0 = p[0]; pb1 = p[64]; pb2 = p[128];
    }
    __syncthreads();

    // ---------------- P3: states -> SE|SA|SQ. A in regs (fixed mt), B double-buffered ----------------
    {
        const u16* ap = STh + (mt*16 + fl)*136 + kg*8;
        short8 a0 = lds8(ap), a1 = lds8(ap+32), a2 = lds8(ap+64);
        short8 b0 = pb0, b1 = pb1, b2 = pb2;
        #pragma unroll
        for (int k = 0; k < 6; ++k) {
            const int nt = nb + 4*k;
            short8 c0 = b0, c1 = b1, c2 = b2;
            if (k < 5) {
                const short8* p = (const short8*)(F3 + (((nb + 4*(k+1))*3)*64 + lane)*8);
                b0 = p[0]; b1 = p[64]; b2 = p[128];
            }
            f32x4 acc = {0.f,0.f,0.f,0.f};
            acc = MFMA(a0, c0, acc); acc = MFMA(a1, c1, acc); acc = MFMA(a2, c2, acc);
            u16* dst; const float* bias; int colOff;
            if (nt < 8)       { dst = SEh; bias = sb;  colOff = nt*16; }
            else if (nt < 16) { dst = SAh; bias = sab; colOff = (nt-8)*16; }
            else              { dst = SQh; bias = sqb; colOff = (nt-16)*16; }
            float bv = bias[colOff + fl];
            int rowb = mt*16 + kg*4;
            #pragma unroll
            for (int r = 0; r < 4; ++r)
                dst[(rowb+r)*136 + colOff + fl] = f2b(lk(acc[r] + bv));
        }
    }
    // cross-barrier prefetch: P4 first B-tile
    short8 qb0, qb1, qb2, qb3;
    {
        const short8* p = (const short8*)(F4 + ((nb*4)*64 + lane)*8);
        qb0 = p[0]; qb1 = p[64]; qb2 = p[128]; qb3 = p[192];
    }
    __syncthreads();

    // ---------------- P4: Q|K|V. A in regs (SE for k<2, SA after), B double-buffered ----------------
    {
        const u16* apSE = SEh + (mt*16 + fl)*136 + kg*8;
        short8 a0 = lds8(apSE), a1 = lds8(apSE+32), a2 = lds8(apSE+64), a3 = lds8(apSE+96);
        short8 b0 = qb0, b1 = qb1, b2 = qb2, b3 = qb3;
        #pragma unroll
        for (int k = 0; k < 6; ++k) {
            const int nt = nb + 4*k;
            if (k == 2) {   // switch A source: SE -> SA
                const u16* apSA = SAh + (mt*16 + fl)*136 + kg*8;
                a0 = lds8(apSA); a1 = lds8(apSA+32); a2 = lds8(apSA+64); a3 = lds8(apSA+96);
            }
            short8 c0 = b0, c1 = b1, c2 = b2, c3 = b3;
            if (k < 5) {
                const short8* p = (const short8*)(F4 + (((nb + 4*(k+1))*4)*64 + lane)*8);
                b0 = p[0]; b1 = p[64]; b2 = p[128]; b3 = p[192];
            }
            f32x4 acc = {0.f,0.f,0.f,0.f};
            acc = MFMA(a0, c0, acc); acc = MFMA(a1, c1, acc);
            acc = MFMA(a2, c2, acc); acc = MFMA(a3, c3, acc);
            int rowb = mt*16 + kg*4;
            if (nt < 8) {
                float bv = qb[nt*16 + fl];
                #pragma unroll
                for (int r = 0; r < 4; ++r)
                    Qh[(rowb+r)*136 + nt*16 + fl] = f2b((acc[r] + bv)*0.08838834764831845f);
            } else if (nt < 16) {
                float bv = kb[(nt-8)*16 + fl];
                #pragma unroll
                for (int r = 0; r < 4; ++r)
                    Kh[(rowb+r)*136 + (nt-8)*16 + fl] = f2b(acc[r] + bv);
            } else {
                int c = (nt-16)*16 + fl;
                float bv = vb[c];
                #pragma unroll
                for (int r = 0; r < 4; ++r)
                    Vt[c*40 + rowb + r] = f2b(acc[r] + bv);
            }
        }
    }
    __syncthreads();

    // ---------------- P5+P6 merged: score + in-wave softmax (waves 0,1) ----------------
    if (wv < 2) {
        const u16* ap = Qh + (wv*16 + fl)*136 + kg*8;
        short8 a0 = lds8(ap), a1 = lds8(ap+32), a2 = lds8(ap+64), a3 = lds8(ap+96);
        const u16* bp0 = Kh + fl*136 + kg*8;          // K rows 0..15  -> cols 0..15
        const u16* bp1 = Kh + (16 + fl)*136 + kg*8;   // K rows 16..31 -> cols 16..31
        f32x4 acc0 = {0.f,0.f,0.f,0.f}, acc1 = {0.f,0.f,0.f,0.f};
        acc0 = MFMA(a0, lds8(bp0), acc0);     acc0 = MFMA(a1, lds8(bp0+32), acc0);
        acc0 = MFMA(a2, lds8(bp0+64), acc0);  acc0 = MFMA(a3, lds8(bp0+96), acc0);
        acc1 = MFMA(a0, lds8(bp1), acc1);     acc1 = MFMA(a1, lds8(bp1+32), acc1);
        acc1 = MFMA(a2, lds8(bp1+64), acc1);  acc1 = MFMA(a3, lds8(bp1+96), acc1);
        #pragma unroll
        for (int r = 0; r < 4; ++r) {
            const int n = wv*16 + kg*4 + r;
            const int m0 = fl, m1 = fl + 16;
            float e0 = (m0 == n) ? -3e38f : acc0[r];
            float e1 = (m1 == n) ? -3e38f : acc1[r];
            float mx = fmaxf(e0, e1);
            #pragma unroll
            for (int d = 8; d; d >>= 1) mx = fmaxf(mx, __shfl_xor(mx, d, 16));
            float x0 = (m0 == n) ? 0.f : __expf(e0 - mx);
            float x1 = (m1 == n) ? 0.f : __expf(e1 - mx);
            float s = x0 + x1;
            #pragma unroll
            for (int d = 8; d; d >>= 1) s += __shfl_xor(s, d, 16);
            float inv = 1.f/s;
            float w0 = x0*inv, w1 = x1*inv;
            W32h[n*40 + m0] = f2b(w0);           // diag lane stores exact 0
            W32h[n*40 + m1] = f2b(w1);
            float* wp = outw + (b*32 + n)*31;
            if (m0 != n) wp[(m0 < n) ? m0 : m0-1] = w0;
            if (m1 != n) wp[(m1 < n) ? m1 : m1-1] = w1;
        }
    }
    __syncthreads();

    // ---------------- P7: agg = W32 @ V ;  prefetch P8 B-frags first ----------------
    short8 f80,f81,f82,f83,f84,f85,f86,f87;
    {
        const short8* p = (const short8*)(F8 + ((nb*8)*64 + lane)*8);
        f80=p[0]; f81=p[64]; f82=p[128]; f83=p[192]; f84=p[256]; f85=p[320]; f86=p[384]; f87=p[448];
    }
    for (int t = wv; t < 16; t += 8) {
        int nt = t >> 1, m7 = t & 1;
        f32x4 acc = {0.f,0.f,0.f,0.f};
        acc = MFMA(lds8(W32h + (m7*16 + fl)*40 + kg*8),
                   lds8(Vt + (nt*16 + fl)*40 + kg*8), acc);
        int rowb = m7*16 + kg*4;
        #pragma unroll
        for (int r = 0; r < 4; ++r)
            AGGh[(rowb+r)*136 + nt*16 + fl] = f2b(acc[r]);
    }
    __syncthreads();

    // ---------------- P8: f1 (K=256 split sq|agg), B pre-loaded in regs ----------------
    {
        f32x4 acc = {0.f,0.f,0.f,0.f};
        const u16* aq = SQh  + (mt*16 + fl)*136 + kg*8;
        const u16* ag = AGGh + (mt*16 + fl)*136 + kg*8;
        acc = MFMA(lds8(aq),      f80, acc);
        acc = MFMA(lds8(aq+32),   f81, acc);
        acc = MFMA(lds8(aq+64),   f82, acc);
        acc = MFMA(lds8(aq+96),   f83, acc);
        acc = MFMA(lds8(ag),      f84, acc);
        acc = MFMA(lds8(ag+32),   f85, acc);
        acc = MFMA(lds8(ag+64),   f86, acc);
        acc = MFMA(lds8(ag+96),   f87, acc);
        float bv = f1b[nb*16 + fl];
        int rowb = mt*16 + kg*4;
        #pragma unroll
        for (int r = 0; r < 4; ++r)
            H1h[(rowb+r)*72 + nb*16 + fl] = f2b(lk(acc[r] + bv));
    }
    // cross-barrier prefetch: P9 B
    short8 b9a, b9b;
    {
        const short8* p = (const short8*)(F9 + lane*8);
        b9a = p[0]; b9b = p[64];
    }
    __syncthreads();

    // ---------------- P9: f2 -> value out (waves 0,1) ----------------
    if (wv < 2) {
        f32x4 acc = {0.f,0.f,0.f,0.f};
        const u16* ap = H1h + (wv*16 + fl)*72 + kg*8;
        acc = MFMA(lds8(ap), b9a, acc);
        acc = MFMA(lds8(ap+32), b9b, acc);
        float bv = f2b_[fl];
        int rowb = wv*16 + kg*4;
        #pragma unroll
        for (int r = 0; r < 4; ++r)
            outv[(b*32 + rowb + r)*16 + fl] = acc[r] + bv;
    }
}

extern "C" void kernel_launch(void* const* d_in, const int* in_sizes, int n_in,
                              void* d_out, int out_size, void* d_ws, size_t ws_size,
                              hipStream_t stream) {
    const int B = in_sizes[0] / (32*75);
    u16* frag = (u16*)d_ws;

    const int PRE_GRID = (FRAG_TOTAL + 255)/256;
    prelude_k<<<PRE_GRID, 256, 0, stream>>>(
        (const float*)d_in[11], (const float*)d_in[9],  (const float*)d_in[19],
        (const float*)d_in[15], (const float*)d_in[13], (const float*)d_in[17],
        (const float*)d_in[21], (const float*)d_in[23], frag);

    fused_kernel<<<B, 512, 0, stream>>>(
        (const float*)d_in[0],  (const float*)d_in[1],  (const float*)d_in[2],
        (const float*)d_in[4],
        (const float*)d_in[5],  (const float*)d_in[6],
        (const float*)d_in[7],  (const float*)d_in[8],
        (const float*)d_in[12], (const float*)d_in[10], (const float*)d_in[20],
        (const float*)d_in[16], (const float*)d_in[14], (const float*)d_in[18],
        (const float*)d_in[22], (const float*)d_in[24],
        (float*)d_out, (float*)d_out + (size_t)B*32*16, frag);
}